// Round 11
// baseline (75.033 us; speedup 1.0000x reference)
//
#include <hip/hip_runtime.h>
#include <hip/hip_fp16.h>
#include <math.h>

#ifndef __has_builtin
#define __has_builtin(x) 0
#endif

#define GRIDC  32          // cells per axis (256 px / 8 px)
#define NCELL  1024
#define CSHIFT 3           // 8 px cells
#define RAD    4           // +-4 cells => all nodes within 32 px included.
                           // RAD must stay 4 (see R8 note); additionally each
                           // row's x-span is clipped to the 32px disk
                           // (over-inclusive rounding only -> still exact).

__device__ __forceinline__ float fast_exp2(float x) {
#if __has_builtin(__builtin_amdgcn_exp2f)
    return __builtin_amdgcn_exp2f(x);
#else
    return exp2f(x);
#endif
}

__device__ __forceinline__ unsigned pk2(float a, float b) {
    __half2 h = __floats2half2_rn(a, b);
    return *reinterpret_cast<unsigned*>(&h);
}

__device__ __forceinline__ int cell_of(int x, int y) {
    int cx = x >> CSHIFT; cx = cx < 0 ? 0 : (cx > GRIDC - 1 ? GRIDC - 1 : cx);
    int cy = y >> CSHIFT; cy = cy < 0 ? 0 : (cy > GRIDC - 1 ? GRIDC - 1 : cy);
    return (cy << 5) + cx;
}

// ---------------------------------------------------------------------------
// Single fused kernel. 512 threads, 128 queries (4 threads/query).
//   Phase 1: bin ALL nodes (<=2048) into LDS as PACKED 16-B records:
//            {(px,py) f16x2 | s f32 | (w0,w1) f16x2 | (w2,0) f16x2}.
//            Coords are integers <=255 -> exact in f16; weights lose ~5e-4.
//   Phase 2: quarter q walks window rows [9q/4,9(q+1)/4); per row the x-span
//            is clipped to the 32px disk (circle pruning, ~20% fewer iters);
//            single ds_read_b128 gather per node (was b128+b64).
// LDS ~42.3 KB. Grid 512 blocks -> 2 blocks/CU, 16 waves/CU.
// ---------------------------------------------------------------------------
__global__ __launch_bounds__(512) void rbf_fused(const int* __restrict__ X,
        const int* __restrict__ pat, const float* __restrict__ W2,
        const float* __restrict__ sig, float* __restrict__ out, int N, int P) {
    __shared__ uint4  sA[2048];        // packed node records  32 KB
    __shared__ int    sst[NCELL + 1];  // counts -> starts      4.1 KB
    __shared__ float4 accb[3 * 128];   // quarter partials      6 KB
    __shared__ int    wsum[8];

    const int tid  = threadIdx.x;
    const int lane = tid & 63;
    const int wv   = tid >> 6;

    // ---- Phase 1a: zero counts ----
    for (int i = tid; i < NCELL + 1; i += 512) sst[i] = 0;
    __syncthreads();

    // ---- Phase 1b: histogram (up to 4 nodes/thread, coalesced) ----
    int cellr[4], slotr[4], xr[4], yr[4];
#pragma unroll
    for (int j = 0; j < 4; ++j) {
        int p = j * 512 + tid;
        cellr[j] = -1;
        if (p < P) {
            int2 xy = ((const int2*)pat)[p];
            xr[j] = xy.x; yr[j] = xy.y;
            int c = cell_of(xy.x, xy.y);
            cellr[j] = c;
            slotr[j] = atomicAdd(&sst[c], 1);
        }
    }
    __syncthreads();

    // ---- Phase 1c: exclusive scan of 1024 counts (thread owns 2 cells) ----
    const int c0 = sst[2 * tid], c1 = sst[2 * tid + 1];
    int sum = c0 + c1;
    int incl = sum;
#pragma unroll
    for (int off = 1; off < 64; off <<= 1) {
        int t = __shfl_up(incl, off);
        if (lane >= off) incl += t;
    }
    if (lane == 63) wsum[wv] = incl;
    __syncthreads();
    int base = 0;
#pragma unroll
    for (int w = 0; w < 8; ++w) base += (w < wv) ? wsum[w] : 0;
    const int excl0 = base + incl - sum;
    __syncthreads();
    sst[2 * tid + 0] = excl0;
    sst[2 * tid + 1] = excl0 + c0;
    if (tid == 511) sst[NCELL] = excl0 + c0 + c1;
    __syncthreads();

    // ---- Phase 1d: scatter packed node records into cell-sorted LDS ----
#pragma unroll
    for (int j = 0; j < 4; ++j) {
        if (cellr[j] >= 0) {
            int p = j * 512 + tid;
            int pos = sst[cellr[j]] + slotr[j];
            uint4 rec;
            rec.x = pk2((float)xr[j], (float)yr[j]);
            rec.y = __float_as_uint(-0.7213475204444817f / sig[p]);
            rec.z = pk2(W2[p], W2[P + p]);
            rec.w = pk2(W2[2 * P + p], 0.f);
            sA[pos] = rec;
        }
    }
    __syncthreads();

    // ---- Phase 2: RBF, 4 threads per query (window rows split 2/2/2/3) ----
    const int quarter = tid >> 7;          // 0..3
    const int qi      = tid & 127;
    const int n       = blockIdx.x * 128 + qi;
    const bool act    = n < N;

    float den = 0.f, acc0 = 0.f, acc1 = 0.f, acc2 = 0.f;
    if (act) {
        int2 xy = ((const int2*)X)[n];
        const int   xi = xy.x, yi = xy.y;
        const float xf = (float)xi, yf = (float)yi;
        int cx = xi >> CSHIFT; cx = cx < 0 ? 0 : (cx > GRIDC - 1 ? GRIDC - 1 : cx);
        int cy = yi >> CSHIFT; cy = cy < 0 ? 0 : (cy > GRIDC - 1 ? GRIDC - 1 : cy);
        const int x0 = cx - RAD < 0 ? 0 : cx - RAD;
        const int x1 = cx + RAD > GRIDC - 1 ? GRIDC - 1 : cx + RAD;
        const int r0 = (9 * quarter) >> 2;         // 0,2,4,6
        const int r1 = (9 * (quarter + 1)) >> 2;   // 2,4,6,9
        for (int r = r0; r < r1; ++r) {
            int gy = cy - RAD + r;
            if ((unsigned)gy >= GRIDC) continue;
            // circle pruning: min |dy| from query to this row of cells
            int d1 = (gy << 3) - yi;
            int d2 = yi - ((gy << 3) + 7);
            int dmin = d1 > d2 ? d1 : d2; dmin = dmin > 0 ? dmin : 0;
            int rem = 1024 - dmin * dmin;
            if (rem <= 0) continue;
            int xrad = (int)ceilf(sqrtf((float)rem));   // over-inclusive: safe
            int gxlo = (xi - xrad) >> 3;                // ceil((xi-7-xrad)/8)
            int gxhi = (xi + xrad) >> 3;
            int xs = gxlo > x0 ? gxlo : x0;
            int xe = gxhi < x1 ? gxhi : x1;
            if (xs > xe) continue;
            int row = gy << 5;
            int k0 = sst[row + xs];
            int k1 = sst[row + xe + 1];
            if (k0 >= k1) continue;
            uint4 a = sA[k0];                           // software pipeline
            for (int k = k0; k < k1; ++k) {
                int kn = k + 1 < k1 ? k + 1 : k;
                uint4 an = sA[kn];
                __half2 hxy = *reinterpret_cast<__half2*>(&a.x);
                float px = __low2float(hxy), py = __high2float(hxy);
                float s  = __uint_as_float(a.y);
                __half2 hw01 = *reinterpret_cast<__half2*>(&a.z);
                float w0 = __low2float(hw01), w1 = __high2float(hw01);
                float w2v = __low2float(*reinterpret_cast<__half2*>(&a.w));
                float dx = xf - px;
                float dy = yf - py;
                float rr = fast_exp2(fmaf(dy, dy, dx * dx) * s);
                den  += rr;
                acc0 = fmaf(rr, w0, acc0);
                acc1 = fmaf(rr, w1, acc1);
                acc2 = fmaf(rr, w2v, acc2);
                a = an;
            }
        }
    }

    if (quarter) accb[(quarter - 1) * 128 + qi] = make_float4(den, acc0, acc1, acc2);
    __syncthreads();
    if (quarter == 0 && act) {
#pragma unroll
        for (int w = 0; w < 3; ++w) {
            float4 u = accb[w * 128 + qi];
            den += u.x; acc0 += u.y; acc1 += u.z; acc2 += u.w;
        }
        float inv = 1.0f / den;
        out[3 * n + 0] = acc0 * inv;
        out[3 * n + 1] = acc1 * inv;
        out[3 * n + 2] = acc2 * inv;
    }
}

// ---------------------------------------------------------------------------
// Generic fallback (unexpected sizes): brute-force N x P sweep.
// ---------------------------------------------------------------------------
__global__ void pack_nodes(const int* __restrict__ pat, const float* __restrict__ W2,
                           const float* __restrict__ sigmaSq, float* __restrict__ nodes,
                           int P) {
    int p = blockIdx.x * blockDim.x + threadIdx.x;
    if (p >= P) return;
    float* q = nodes + 8 * (size_t)p;
    q[0] = (float)pat[2 * p];
    q[1] = (float)pat[2 * p + 1];
    q[2] = -0.7213475204444817f / sigmaSq[p];
    q[3] = W2[p];
    q[4] = W2[P + p];
    q[5] = W2[2 * P + p];
    q[6] = 0.0f;
    q[7] = 0.0f;
}

__global__ __launch_bounds__(256) void rbf_main_dyn(const int* __restrict__ X,
                                                    const float* __restrict__ nodes,
                                                    float* __restrict__ outp,
                                                    int N, int P) {
    int n = blockIdx.x * 256 + threadIdx.x;
    if (n >= N) return;
    float xn = (float)X[2 * n], yn = (float)X[2 * n + 1];
    float den = 0.f, a0 = 0.f, a1 = 0.f, a2 = 0.f;
    for (int j = 0; j < P; ++j) {
        const float* q = nodes + (size_t)j * 8;
        float dx = xn - q[0], dy = yn - q[1];
        float r = fast_exp2(fmaf(dy, dy, dx * dx) * q[2]);
        den += r;
        a0 = fmaf(r, q[3], a0);
        a1 = fmaf(r, q[4], a1);
        a2 = fmaf(r, q[5], a2);
    }
    outp[3 * n + 0] = a0 / den;
    outp[3 * n + 1] = a1 / den;
    outp[3 * n + 2] = a2 / den;
}

extern "C" void kernel_launch(void* const* d_in, const int* in_sizes, int n_in,
                              void* d_out, int out_size, void* d_ws, size_t ws_size,
                              hipStream_t stream) {
    const int*   X   = (const int*)d_in[0];
    const int*   pat = (const int*)d_in[1];
    const float* W2  = (const float*)d_in[2];
    const float* sig = (const float*)d_in[3];
    float*       out = (float*)d_out;

    const int N = in_sizes[0] / 2;
    const int P = in_sizes[3];

    if (P <= 2048 && out_size == 3 * N) {
        rbf_fused<<<dim3((N + 127) / 128), dim3(512), 0, stream>>>(
            X, pat, W2, sig, out, N, P);
    } else {
        float* nodes = (float*)d_ws;
        pack_nodes<<<dim3((P + 255) / 256), dim3(256), 0, stream>>>(pat, W2, sig, nodes, P);
        rbf_main_dyn<<<dim3((N + 255) / 256), dim3(256), 0, stream>>>(X, nodes, out, N, P);
    }
}

// Round 12
// 73.465 us; speedup vs baseline: 1.0213x; 1.0213x over previous
//
#include <hip/hip_runtime.h>
#include <hip/hip_fp16.h>
#include <math.h>

#ifndef __has_builtin
#define __has_builtin(x) 0
#endif

#define GRIDC  32          // cells per axis (256 px / 8 px)
#define NCELL  1024
#define CSHIFT 3           // 8 px cells
#define RAD    4           // +-4 cells => all nodes within 32 px included.
                           // RAD must stay 4: worst-case query has nearest
                           // node ~13px (den >= e^-85 at sigma^2=1) while a
                           // dropped 30px node with sigma^2=5 has r ~ e^-90;
                           // 32px guarantee keeps dropped/den < 1e-3.
                           // NOTE (R10 post-mortem): per-row circle pruning
                           // REGRESSED — wave cost is max over lanes, and the
                           // max-lane is barely pruned; sqrt/branch overhead
                           // was pure cost. Do not re-add.

__device__ __forceinline__ float fast_exp2(float x) {
#if __has_builtin(__builtin_amdgcn_exp2f)
    return __builtin_amdgcn_exp2f(x);
#else
    return exp2f(x);
#endif
}

__device__ __forceinline__ unsigned pk2(float a, float b) {
    __half2 h = __floats2half2_rn(a, b);
    return *reinterpret_cast<unsigned*>(&h);
}

__device__ __forceinline__ int cell_of(int x, int y) {
    int cx = x >> CSHIFT; cx = cx < 0 ? 0 : (cx > GRIDC - 1 ? GRIDC - 1 : cx);
    int cy = y >> CSHIFT; cy = cy < 0 ? 0 : (cy > GRIDC - 1 ? GRIDC - 1 : cy);
    return (cy << 5) + cx;
}

// ---------------------------------------------------------------------------
// Single fused kernel. 512 threads, 128 queries (4 threads/query).
// Phase 2 is DS-pipe-throughput bound (per-CU shared LDS pipe, random 16-B
// gathers): so node records are packed to ONE ds_read_b128 per node:
//   {(px,py) f16x2 | s f32 | (w0,w1) f16x2 | (w2,0) f16x2}
// Coords are integers <=255 -> exact in f16; weights lose ~5e-4 rel
// (measured absmax 0.0156 vs threshold 0.071).
// LDS ~42.3 KB. Grid 512 blocks -> 2 blocks/CU, 16 waves/CU.
// ---------------------------------------------------------------------------
__global__ __launch_bounds__(512) void rbf_fused(const int* __restrict__ X,
        const int* __restrict__ pat, const float* __restrict__ W2,
        const float* __restrict__ sig, float* __restrict__ out, int N, int P) {
    __shared__ uint4  sA[2048];        // packed node records  32 KB
    __shared__ int    sst[NCELL + 1];  // counts -> starts      4.1 KB
    __shared__ float4 accb[3 * 128];   // quarter partials      6 KB
    __shared__ int    wsum[8];

    const int tid  = threadIdx.x;
    const int lane = tid & 63;
    const int wv   = tid >> 6;

    // ---- Phase 1a: zero counts ----
    for (int i = tid; i < NCELL + 1; i += 512) sst[i] = 0;
    __syncthreads();

    // ---- Phase 1b: histogram (up to 4 nodes/thread, coalesced) ----
    int cellr[4], slotr[4], xr[4], yr[4];
#pragma unroll
    for (int j = 0; j < 4; ++j) {
        int p = j * 512 + tid;
        cellr[j] = -1;
        if (p < P) {
            int2 xy = ((const int2*)pat)[p];
            xr[j] = xy.x; yr[j] = xy.y;
            int c = cell_of(xy.x, xy.y);
            cellr[j] = c;
            slotr[j] = atomicAdd(&sst[c], 1);
        }
    }
    __syncthreads();

    // ---- Phase 1c: exclusive scan of 1024 counts (thread owns 2 cells) ----
    const int c0 = sst[2 * tid], c1 = sst[2 * tid + 1];
    int sum = c0 + c1;
    int incl = sum;
#pragma unroll
    for (int off = 1; off < 64; off <<= 1) {
        int t = __shfl_up(incl, off);
        if (lane >= off) incl += t;
    }
    if (lane == 63) wsum[wv] = incl;
    __syncthreads();
    int base = 0;
#pragma unroll
    for (int w = 0; w < 8; ++w) base += (w < wv) ? wsum[w] : 0;
    const int excl0 = base + incl - sum;
    __syncthreads();
    sst[2 * tid + 0] = excl0;
    sst[2 * tid + 1] = excl0 + c0;
    if (tid == 511) sst[NCELL] = excl0 + c0 + c1;
    __syncthreads();

    // ---- Phase 1d: scatter packed node records into cell-sorted LDS ----
#pragma unroll
    for (int j = 0; j < 4; ++j) {
        if (cellr[j] >= 0) {
            int p = j * 512 + tid;
            int pos = sst[cellr[j]] + slotr[j];
            uint4 rec;
            rec.x = pk2((float)xr[j], (float)yr[j]);
            rec.y = __float_as_uint(-0.7213475204444817f / sig[p]);
            rec.z = pk2(W2[p], W2[P + p]);
            rec.w = pk2(W2[2 * P + p], 0.f);
            sA[pos] = rec;
        }
    }
    __syncthreads();

    // ---- Phase 2: RBF, 4 threads per query (window rows split 2/2/2/3) ----
    const int quarter = tid >> 7;          // 0..3
    const int qi      = tid & 127;
    const int n       = blockIdx.x * 128 + qi;
    const bool act    = n < N;

    float den = 0.f, acc0 = 0.f, acc1 = 0.f, acc2 = 0.f;
    if (act) {
        int2 xy = ((const int2*)X)[n];
        const float xf = (float)xy.x, yf = (float)xy.y;
        int cx = xy.x >> CSHIFT; cx = cx < 0 ? 0 : (cx > GRIDC - 1 ? GRIDC - 1 : cx);
        int cy = xy.y >> CSHIFT; cy = cy < 0 ? 0 : (cy > GRIDC - 1 ? GRIDC - 1 : cy);
        const int x0 = cx - RAD < 0 ? 0 : cx - RAD;
        const int x1 = cx + RAD > GRIDC - 1 ? GRIDC - 1 : cx + RAD;
        const int r0 = (9 * quarter) >> 2;         // 0,2,4,6
        const int r1 = (9 * (quarter + 1)) >> 2;   // 2,4,6,9
        for (int r = r0; r < r1; ++r) {
            int gy = cy - RAD + r;
            if ((unsigned)gy >= GRIDC) continue;
            int row = gy << 5;
            int k0 = sst[row + x0];
            int k1 = sst[row + x1 + 1];
            if (k0 >= k1) continue;
            uint4 a = sA[k0];                       // software pipeline
            for (int k = k0; k < k1; ++k) {
                int kn = k + 1 < k1 ? k + 1 : k;
                uint4 an = sA[kn];
                __half2 hxy = *reinterpret_cast<__half2*>(&a.x);
                float px = __low2float(hxy), py = __high2float(hxy);
                float s  = __uint_as_float(a.y);
                __half2 hw01 = *reinterpret_cast<__half2*>(&a.z);
                float w0 = __low2float(hw01), w1 = __high2float(hw01);
                float w2v = __low2float(*reinterpret_cast<__half2*>(&a.w));
                float dx = xf - px;
                float dy = yf - py;
                float rr = fast_exp2(fmaf(dy, dy, dx * dx) * s);
                den  += rr;
                acc0 = fmaf(rr, w0, acc0);
                acc1 = fmaf(rr, w1, acc1);
                acc2 = fmaf(rr, w2v, acc2);
                a = an;
            }
        }
    }

    if (quarter) accb[(quarter - 1) * 128 + qi] = make_float4(den, acc0, acc1, acc2);
    __syncthreads();
    if (quarter == 0 && act) {
#pragma unroll
        for (int w = 0; w < 3; ++w) {
            float4 u = accb[w * 128 + qi];
            den += u.x; acc0 += u.y; acc1 += u.z; acc2 += u.w;
        }
        float inv = 1.0f / den;
        out[3 * n + 0] = acc0 * inv;
        out[3 * n + 1] = acc1 * inv;
        out[3 * n + 2] = acc2 * inv;
    }
}

// ---------------------------------------------------------------------------
// Generic fallback (unexpected sizes): brute-force N x P sweep.
// ---------------------------------------------------------------------------
__global__ void pack_nodes(const int* __restrict__ pat, const float* __restrict__ W2,
                           const float* __restrict__ sigmaSq, float* __restrict__ nodes,
                           int P) {
    int p = blockIdx.x * blockDim.x + threadIdx.x;
    if (p >= P) return;
    float* q = nodes + 8 * (size_t)p;
    q[0] = (float)pat[2 * p];
    q[1] = (float)pat[2 * p + 1];
    q[2] = -0.7213475204444817f / sigmaSq[p];
    q[3] = W2[p];
    q[4] = W2[P + p];
    q[5] = W2[2 * P + p];
    q[6] = 0.0f;
    q[7] = 0.0f;
}

__global__ __launch_bounds__(256) void rbf_main_dyn(const int* __restrict__ X,
                                                    const float* __restrict__ nodes,
                                                    float* __restrict__ outp,
                                                    int N, int P) {
    int n = blockIdx.x * 256 + threadIdx.x;
    if (n >= N) return;
    float xn = (float)X[2 * n], yn = (float)X[2 * n + 1];
    float den = 0.f, a0 = 0.f, a1 = 0.f, a2 = 0.f;
    for (int j = 0; j < P; ++j) {
        const float* q = nodes + (size_t)j * 8;
        float dx = xn - q[0], dy = yn - q[1];
        float r = fast_exp2(fmaf(dy, dy, dx * dx) * q[2]);
        den += r;
        a0 = fmaf(r, q[3], a0);
        a1 = fmaf(r, q[4], a1);
        a2 = fmaf(r, q[5], a2);
    }
    outp[3 * n + 0] = a0 / den;
    outp[3 * n + 1] = a1 / den;
    outp[3 * n + 2] = a2 / den;
}

extern "C" void kernel_launch(void* const* d_in, const int* in_sizes, int n_in,
                              void* d_out, int out_size, void* d_ws, size_t ws_size,
                              hipStream_t stream) {
    const int*   X   = (const int*)d_in[0];
    const int*   pat = (const int*)d_in[1];
    const float* W2  = (const float*)d_in[2];
    const float* sig = (const float*)d_in[3];
    float*       out = (float*)d_out;

    const int N = in_sizes[0] / 2;
    const int P = in_sizes[3];

    if (P <= 2048 && out_size == 3 * N) {
        rbf_fused<<<dim3((N + 127) / 128), dim3(512), 0, stream>>>(
            X, pat, W2, sig, out, N, P);
    } else {
        float* nodes = (float*)d_ws;
        pack_nodes<<<dim3((P + 255) / 256), dim3(256), 0, stream>>>(pat, W2, sig, nodes, P);
        rbf_main_dyn<<<dim3((N + 255) / 256), dim3(256), 0, stream>>>(X, nodes, out, N, P);
    }
}